// Round 1
// baseline (427.379 us; speedup 1.0000x reference)
//
#include <hip/hip_runtime.h>
#include <math.h>

#define HH 32
#define WW 32
#define HWSZ 1024      // H*W
#define CC 384
#define NHEAD 12
#define NGROUP 6
#define HC 32
#define GC 64
#define NS 1024        // n_sample
#define ATTN_SCALE 0.17677669529663687f  // 32^-0.5

// ---------------------------------------------------------------------------
// Generic 1x1-conv GEMM: Y[b,o,n] = sum_c W[o,c] * X[b,c,n] + bias[o]
// M=K=384, N=1024, batch via blockIdx.z. 64x64 tile, 4x4 microtile.
// ---------------------------------------------------------------------------
__global__ __launch_bounds__(256) void gemm_bias_kernel(
    const float* __restrict__ W, const float* __restrict__ bias,
    const float* __restrict__ X, float* __restrict__ Y)
{
    const int bz = blockIdx.z;
    const float* Xb = X + (size_t)bz * CC * 1024;
    float* Yb = Y + (size_t)bz * CC * 1024;
    const int tm = blockIdx.y * 64;
    const int tn = blockIdx.x * 64;
    const int tid = threadIdx.x;
    const int tx = tid & 15, ty = tid >> 4;

    __shared__ float sW[16][68];   // [k][m]
    __shared__ float sX[16][68];   // [k][n]

    float acc[4][4] = {};

    for (int k0 = 0; k0 < CC; k0 += 16) {
        {   // W tile: 64 m x 16 k, each thread 4 consecutive k (float4)
            int idx = tid * 4;
            int m = idx >> 4;
            int kk = idx & 15;
            float4 w4 = *(const float4*)&W[(size_t)(tm + m) * CC + k0 + kk];
            sW[kk + 0][m] = w4.x; sW[kk + 1][m] = w4.y;
            sW[kk + 2][m] = w4.z; sW[kk + 3][m] = w4.w;
        }
        {   // X tile: 16 k x 64 n, float4 along n
            int idx = tid * 4;
            int kk = idx >> 6;
            int n = idx & 63;
            *(float4*)&sX[kk][n] = *(const float4*)&Xb[(size_t)(k0 + kk) * 1024 + tn + n];
        }
        __syncthreads();
#pragma unroll
        for (int kk = 0; kk < 16; ++kk) {
            float a[4], bb[4];
            *(float4*)a  = *(const float4*)&sW[kk][ty * 4];
            *(float4*)bb = *(const float4*)&sX[kk][tx * 4];
#pragma unroll
            for (int i = 0; i < 4; ++i)
#pragma unroll
                for (int j = 0; j < 4; ++j)
                    acc[i][j] += a[i] * bb[j];
        }
        __syncthreads();
    }

#pragma unroll
    for (int i = 0; i < 4; ++i) {
        int m = tm + ty * 4 + i;
        float bv = bias[m];
        float4 r;
        r.x = acc[i][0] + bv; r.y = acc[i][1] + bv;
        r.z = acc[i][2] + bv; r.w = acc[i][3] + bv;
        *(float4*)&Yb[(size_t)m * 1024 + tn + tx * 4] = r;
    }
}

// ---------------------------------------------------------------------------
// Depthwise 7x7 conv on q_off = q viewed as [12, 64, 32, 32]; zero pad 3.
// Block per (bg, c) pair; plane staged in LDS.
// ---------------------------------------------------------------------------
__global__ __launch_bounds__(256) void dwconv_kernel(
    const float* __restrict__ q, const float* __restrict__ dww,
    const float* __restrict__ dwb, float* __restrict__ oconv)
{
    const int bc = blockIdx.x;           // 0..767
    const int bg = bc >> 6, c = bc & 63;
    const int b = bg / 6, g = bg % 6;
    const float* plane = q + ((size_t)b * CC + g * 64 + c) * 1024;

    __shared__ float sp[1024];
    __shared__ float sw[49];
    const int tid = threadIdx.x;
    for (int i = tid; i < 1024; i += 256) sp[i] = plane[i];
    if (tid < 49) sw[tid] = dww[c * 49 + tid];
    __syncthreads();

    const float bias = dwb[c];
    for (int i = tid; i < 1024; i += 256) {
        int y = i >> 5, x = i & 31;
        float s = 0.f;
#pragma unroll
        for (int ky = 0; ky < 7; ++ky) {
            int yy = y + ky - 3;
            if (yy < 0 || yy > 31) continue;
#pragma unroll
            for (int kx = 0; kx < 7; ++kx) {
                int xx = x + kx - 3;
                if (xx < 0 || xx > 31) continue;
                s += sp[yy * 32 + xx] * sw[ky * 7 + kx];
            }
        }
        oconv[(size_t)bc * 1024 + i] = s + bias;
    }
}

// ---------------------------------------------------------------------------
// LayerNorm(channels=64) + exact GELU + 1x1->2ch + tanh*2/32 + ref points
// Block per bg (12 blocks). pos stored [bg, s, 2] (y, x).
// ---------------------------------------------------------------------------
__global__ __launch_bounds__(256) void offset_kernel(
    const float* __restrict__ oconv, const float* __restrict__ lng,
    const float* __restrict__ lnb, const float* __restrict__ pw,
    float* __restrict__ pos)
{
    const int bg = blockIdx.x;
    const int tid = threadIdx.x;
    const float* base = oconv + (size_t)bg * 64 * 1024;

    for (int px = tid; px < 1024; px += 256) {
        float sum = 0.f;
        for (int c = 0; c < 64; ++c) sum += base[(size_t)c * 1024 + px];
        float mu = sum * (1.f / 64.f);
        float var = 0.f;
        for (int c = 0; c < 64; ++c) {
            float d = base[(size_t)c * 1024 + px] - mu;
            var += d * d;
        }
        var *= (1.f / 64.f);
        float inv = rsqrtf(var + 1e-5f);
        float offy = 0.f, offx = 0.f;
        for (int c = 0; c < 64; ++c) {
            float v = (base[(size_t)c * 1024 + px] - mu) * inv * lng[c] + lnb[c];
            float gelu = 0.5f * v * (1.f + erff(v * 0.70710678118654752440f));
            offy += gelu * pw[c];
            offx += gelu * pw[64 + c];
        }
        offy = tanhf(offy) * (2.0f / 32.0f);
        offx = tanhf(offx) * (2.0f / 32.0f);
        int y = px >> 5, x = px & 31;
        float ry = ((y + 0.5f) / 32.f) * 2.f - 1.f;
        float rx = ((x + 0.5f) / 32.f) * 2.f - 1.f;
        pos[((size_t)bg * 1024 + px) * 2 + 0] = offy + ry;
        pos[((size_t)bg * 1024 + px) * 2 + 1] = offx + rx;
    }
}

// ---------------------------------------------------------------------------
// Bilinear grid-sample of x at pos (align_corners=True, zeros pad).
// One thread per (b, c, s) output element; x_s stored [2, 384, 1024].
// ---------------------------------------------------------------------------
__global__ __launch_bounds__(256) void sample_kernel(
    const float* __restrict__ x, const float* __restrict__ pos,
    float* __restrict__ xs)
{
    const int idx = blockIdx.x * 256 + threadIdx.x;   // 786432 total
    const int s = idx & 1023;
    const int bc = idx >> 10;
    const int c = bc % CC;
    const int b = bc / CC;
    const int bg = b * 6 + (c >> 6);

    float py = pos[((size_t)bg * 1024 + s) * 2 + 0];
    float px = pos[((size_t)bg * 1024 + s) * 2 + 1];
    float gx = (px + 1.f) * 0.5f * 31.f;
    float gy = (py + 1.f) * 0.5f * 31.f;
    float x0f = floorf(gx), y0f = floorf(gy);
    float wx = gx - x0f, wy = gy - y0f;
    int x0 = (int)x0f, y0 = (int)y0f;

    const float* plane = x + (size_t)bc * 1024;
    float acc = 0.f;
    if ((unsigned)x0       <= 31u && (unsigned)y0       <= 31u) acc += plane[y0 * 32 + x0]           * (1.f - wx) * (1.f - wy);
    if ((unsigned)(x0 + 1) <= 31u && (unsigned)y0       <= 31u) acc += plane[y0 * 32 + x0 + 1]       * wx * (1.f - wy);
    if ((unsigned)x0       <= 31u && (unsigned)(y0 + 1) <= 31u) acc += plane[(y0 + 1) * 32 + x0]     * (1.f - wx) * wy;
    if ((unsigned)(x0 + 1) <= 31u && (unsigned)(y0 + 1) <= 31u) acc += plane[(y0 + 1) * 32 + x0 + 1] * wx * wy;
    xs[idx] = acc;
}

// ---------------------------------------------------------------------------
// Attention: block per (bh, 8-query tile). Scores+RPE bias in regs,
// softmax via wave+LDS reduce, probs in padded LDS, PV one (hc,mq)/thread.
// ---------------------------------------------------------------------------
__global__ __launch_bounds__(256) void attn_kernel(
    const float* __restrict__ q, const float* __restrict__ k,
    const float* __restrict__ v, const float* __restrict__ pos,
    const float* __restrict__ rpe, float* __restrict__ out)
{
    const int bh = blockIdx.y;           // 0..23
    const int m0 = blockIdx.x * 8;
    const int b = bh / 12, head = bh % 12;
    const int bg = b * 6 + (head >> 1);
    const int tid = threadIdx.x;
    const int lane = tid & 63, wv = tid >> 6;

    const float* qb = q + ((size_t)b * CC + head * 32) * 1024;
    const float* kb = k + ((size_t)b * CC + head * 32) * 1024;
    const float* vb = v + ((size_t)b * CC + head * 32) * 1024;
    const float* rp = rpe + (size_t)head * (63 * 63);
    const float* pg = pos + (size_t)bg * 1024 * 2;

    __shared__ float sq[32][8];          // [hc][mq]
    __shared__ float sp[8][1028];        // unnormalized probs (padded)
    __shared__ float rmax[4][8], rsum[4][8];

    {
        int hc = tid >> 3, mq = tid & 7;
        sq[hc][mq] = qb[(size_t)hc * 1024 + m0 + mq];
    }
    __syncthreads();

    // ---- scores: QK^T ----
    float sc[8][4];
#pragma unroll
    for (int mq = 0; mq < 8; ++mq)
#pragma unroll
        for (int j = 0; j < 4; ++j) sc[mq][j] = 0.f;

#pragma unroll 4
    for (int hc = 0; hc < 32; ++hc) {
        float qv[8];
#pragma unroll
        for (int mq = 0; mq < 8; ++mq) qv[mq] = sq[hc][mq];
        const float* krow = kb + (size_t)hc * 1024;
#pragma unroll
        for (int j = 0; j < 4; ++j) {
            float kv = krow[tid + j * 256];
#pragma unroll
            for (int mq = 0; mq < 8; ++mq) sc[mq][j] += qv[mq] * kv;
        }
    }

    // ---- query reference points ----
    float qyv[8], qxv[8];
#pragma unroll
    for (int mq = 0; mq < 8; ++mq) {
        int m = m0 + mq;
        qyv[mq] = (((m >> 5) + 0.5f) / 32.f) * 2.f - 1.f;
        qxv[mq] = (((m & 31) + 0.5f) / 32.f) * 2.f - 1.f;
    }

    // ---- scale + RPE bias ----
#pragma unroll
    for (int j = 0; j < 4; ++j) {
        int n = tid + j * 256;
        float py = pg[n * 2 + 0];
        float px = pg[n * 2 + 1];
#pragma unroll
        for (int mq = 0; mq < 8; ++mq) {
            float dy = (qyv[mq] - py) * 0.5f;
            float dx = (qxv[mq] - px) * 0.5f;
            float gx = (dx + 1.f) * 31.f;   // (dx+1)*0.5*62
            float gy = (dy + 1.f) * 31.f;
            float x0f = floorf(gx), y0f = floorf(gy);
            float wx = gx - x0f, wy = gy - y0f;
            int x0 = (int)x0f, y0 = (int)y0f;
            float bias = 0.f;
            if ((unsigned)x0       <= 62u && (unsigned)y0       <= 62u) bias += rp[y0 * 63 + x0]           * (1.f - wx) * (1.f - wy);
            if ((unsigned)(x0 + 1) <= 62u && (unsigned)y0       <= 62u) bias += rp[y0 * 63 + x0 + 1]       * wx * (1.f - wy);
            if ((unsigned)x0       <= 62u && (unsigned)(y0 + 1) <= 62u) bias += rp[(y0 + 1) * 63 + x0]     * (1.f - wx) * wy;
            if ((unsigned)(x0 + 1) <= 62u && (unsigned)(y0 + 1) <= 62u) bias += rp[(y0 + 1) * 63 + x0 + 1] * wx * wy;
            sc[mq][j] = sc[mq][j] * ATTN_SCALE + bias;
        }
    }

    // ---- softmax: block max per mq ----
    float Mv[8];
#pragma unroll
    for (int mq = 0; mq < 8; ++mq) {
        float mv = fmaxf(fmaxf(sc[mq][0], sc[mq][1]), fmaxf(sc[mq][2], sc[mq][3]));
#pragma unroll
        for (int off = 32; off; off >>= 1) mv = fmaxf(mv, __shfl_down(mv, off));
        if (lane == 0) rmax[wv][mq] = mv;
    }
    __syncthreads();
#pragma unroll
    for (int mq = 0; mq < 8; ++mq)
        Mv[mq] = fmaxf(fmaxf(rmax[0][mq], rmax[1][mq]), fmaxf(rmax[2][mq], rmax[3][mq]));

    // ---- exp + store probs + block sum per mq ----
#pragma unroll
    for (int mq = 0; mq < 8; ++mq) {
        float s = 0.f;
#pragma unroll
        for (int j = 0; j < 4; ++j) {
            float p = expf(sc[mq][j] - Mv[mq]);
            sp[mq][tid + j * 256] = p;
            s += p;
        }
#pragma unroll
        for (int off = 32; off; off >>= 1) s += __shfl_down(s, off);
        if (lane == 0) rsum[wv][mq] = s;
    }
    __syncthreads();

    // ---- PV: one (hc, mq) pair per thread ----
    {
        int hc = tid >> 3, mq = tid & 7;
        float invL = 1.f / (rsum[0][mq] + rsum[1][mq] + rsum[2][mq] + rsum[3][mq]);
        const float* vrow = vb + (size_t)hc * 1024;
        const float* prow = sp[mq];
        float acc = 0.f;
#pragma unroll 4
        for (int n = 0; n < 1024; n += 4) {
            float4 pv = *(const float4*)&prow[n];
            float4 vvv = *(const float4*)&vrow[n];
            acc += pv.x * vvv.x + pv.y * vvv.y + pv.z * vvv.z + pv.w * vvv.w;
        }
        out[((size_t)b * CC + head * 32 + hc) * 1024 + m0 + mq] = acc * invL;
    }
}

// ---------------------------------------------------------------------------
extern "C" void kernel_launch(void* const* d_in, const int* in_sizes, int n_in,
                              void* d_out, int out_size, void* d_ws, size_t ws_size,
                              hipStream_t stream) {
    const float* x   = (const float*)d_in[0];
    const float* Wq  = (const float*)d_in[1];
    const float* bq  = (const float*)d_in[2];
    const float* Wk  = (const float*)d_in[3];
    const float* bk  = (const float*)d_in[4];
    const float* Wv  = (const float*)d_in[5];
    const float* bv  = (const float*)d_in[6];
    const float* Wo  = (const float*)d_in[7];
    const float* bo  = (const float*)d_in[8];
    const float* dww = (const float*)d_in[9];
    const float* dwb = (const float*)d_in[10];
    const float* lng = (const float*)d_in[11];
    const float* lnb = (const float*)d_in[12];
    const float* pw  = (const float*)d_in[13];
    const float* rpe = (const float*)d_in[14];

    float* ws = (float*)d_ws;
    const size_t SZ = 786432;           // 2*384*1024
    float* qbuf  = ws;
    float* xs    = ws + 1 * SZ;
    float* kbuf  = ws + 2 * SZ;
    float* vbuf  = ws + 3 * SZ;
    float* abuf  = ws + 4 * SZ;
    float* oconv = ws + 5 * SZ;         // 12*64*1024
    float* pos   = ws + 6 * SZ;         // 12*1024*2

    dim3 gg(16, 6, 2);
    gemm_bias_kernel<<<gg, 256, 0, stream>>>(Wq, bq, x, qbuf);
    dwconv_kernel<<<768, 256, 0, stream>>>(qbuf, dww, dwb, oconv);
    offset_kernel<<<12, 256, 0, stream>>>(oconv, lng, lnb, pw, pos);
    sample_kernel<<<3072, 256, 0, stream>>>(x, pos, xs);
    gemm_bias_kernel<<<gg, 256, 0, stream>>>(Wk, bk, xs, kbuf);
    gemm_bias_kernel<<<gg, 256, 0, stream>>>(Wv, bv, xs, vbuf);
    attn_kernel<<<dim3(128, 24), 256, 0, stream>>>(qbuf, kbuf, vbuf, pos, rpe, abuf);
    gemm_bias_kernel<<<gg, 256, 0, stream>>>(Wo, bo, abuf, (float*)d_out);
}